// Round 12
// baseline (151.759 us; speedup 1.0000x reference)
//
#include <hip/hip_runtime.h>

#define PAD 10
#define CS 128
#define CSP 148           // CS + 2*PAD
#define AH 4000
#define AW 4000
#define RPT 8             // output rows per wave
#define NBLK (1024*32)    // 1024 tiles x 32 waves/tile; divisible by 8 XCDs

// depth-3 rolling PREP: coords, fast flag, 4 clamped loads into slot S
#define PREPG(S, IXF, IYF)                                                    \
    do {                                                                      \
        const float fx0_ = floorf(IXF), fy0_ = floorf(IYF);                   \
        txs[S] = (IXF) - fx0_; tys[S] = (IYF) - fy0_;                         \
        const int ixi_ = (int)fx0_, iyi_ = (int)fy0_;                         \
        ixis[S] = ixi_; iyis[S] = iyi_;                                       \
        fasts[S] = (ixi_ - 1 >= lo_c) & (ixi_ + 2 <= hi_c) &                  \
                   (iyi_ - 1 >= lo_r) & (iyi_ + 2 <= hi_r);                   \
        int mr_ = gr0 + iyi_ - 1; mr_ = mr_ < 0 ? 0 : (mr_ > AH-4 ? AH-4 : mr_); \
        int mc_ = gc0 + ixi_ - 1; mc_ = mc_ < 0 ? 0 : (mc_ > AW-4 ? AW-4 : mc_); \
        const float* p_ = matrix + (size_t)mr_ * AW + mc_;                    \
        __builtin_memcpy(&qg[S][0], p_,        16);                           \
        __builtin_memcpy(&qg[S][1], p_ + AW,   16);                           \
        __builtin_memcpy(&qg[S][2], p_ + 2*AW, 16);                           \
        __builtin_memcpy(&qg[S][3], p_ + 3*AW, 16);                           \
    } while (0)

__global__ __launch_bounds__(64, 8) void shift_bicubic_kernel(
    const float* __restrict__ matrix,
    const float* __restrict__ theta,
    float* __restrict__ out)
{
    // XCD-contiguous swizzle (R8, verified: FETCH 40->31.5 MB):
    // XCD k owns sids [k*4096,(k+1)*4096) = a 4-tile-row horizontal stripe;
    // tile-major so consecutive blocks on a CU share a tile's window (L1).
    const int bid  = blockIdx.x;
    const int sid  = (bid & 7) * (NBLK/8) + (bid >> 3);
    const int tile = sid >> 5;          // 0..1023, row-major over 32x32 tiles
    const int sub  = sid & 31;          // 32 waves per tile
    const int band = sub >> 1;          // 0..15 -> 8-row band
    const int chal = sub & 1;           // column half (0..1)
    const int i0   = tile >> 5;
    const int i1   = tile & 31;
    const int lane = threadIdx.x;       // 0..63
    const int c    = chal*64 + lane;    // column within tile
    const int r0   = band * RPT;        // first row of this wave
    const int w    = i1*CS + c;
    const int h0   = i0*CS + r0;
    if (w >= AW || h0 >= AH) return;

    const float t00 = theta[tile*6+0], t01 = theta[tile*6+1], t02 = theta[tile*6+2];
    const float t10 = theta[tile*6+3], t11 = theta[tile*6+4], t12 = theta[tile*6+5];

    const float xs  = (2.0f*(float)(c + PAD) + 1.0f) * (1.0f/148.0f) - 1.0f;
    const float ys0 = (2.0f*(float)(r0 + PAD) + 1.0f) * (1.0f/148.0f) - 1.0f;
    const float bx  = fmaf(t00, xs, t02);
    const float by  = fmaf(t10, xs, t12);
    // sample coords advance by exactly t01/t11 per output row
    const float ixf0 = fmaf(fmaf(t01, ys0, bx), 74.0f, 73.5f);
    const float iyf0 = fmaf(fmaf(t11, ys0, by), 74.0f, 73.5f);

    const int gr0 = i0*CS - 2*PAD;
    const int gc0 = i1*CS - 2*PAD;
    const int lo_c = (gc0 < 0) ? -gc0 : 0;
    const int hi_c = (gc0 + CSP - 1 > AW - 1) ? (AW - 1 - gc0) : (CSP - 1);
    const int lo_r = (gr0 < 0) ? -gr0 : 0;
    const int hi_r = (gr0 + CSP - 1 > AH - 1) ? (AH - 1 - gr0) : (CSP - 1);

    // depth-3 rolling pipeline state
    float  txs[3], tys[3];
    int    ixis[3], iyis[3];
    bool   fasts[3];
    float4 qg[3][4];

    PREPG(0, ixf0, iyf0);
    {
        const float ixf1 = ixf0 + t01;
        const float iyf1 = iyf0 + t11;
        PREPG(1, ixf1, iyf1);
    }

    int oidx = h0*AW + w;
    #pragma unroll
    for (int k = 0; k < RPT; ++k) {
        // ---- issue pixel k+2's loads (slot (k+2)%3) ----
        if (k + 2 < RPT) {
            const float ixfn = fmaf((float)(k+2), t01, ixf0);
            const float iyfn = fmaf((float)(k+2), t11, iyf0);
            PREPG((k+2)%3, ixfn, iyfn);
        }
        // fence: loads above may not sink; consumers below may not hoist
        __builtin_amdgcn_sched_barrier(0);

        // ---- consume slot k%3 ----
        const int   S  = k % 3;
        const float tx = txs[S], ty = tys[S];
        const float A_ = -0.75f, AP2 = 1.25f, mAP3 = -2.25f;
        const float sx = 1.0f - tx, sy = 1.0f - ty;
        const float tx2 = tx*tx, sx2 = sx*sx;
        const float ty2 = ty*ty, sy2 = sy*sy;
        const float wx0 = A_*(tx*sx2);
        const float wx3 = A_*(sx*tx2);
        const float wx1 = fmaf(tx2, fmaf(AP2, tx, mAP3), 1.0f);
        const float wx2 = fmaf(sx2, fmaf(AP2, sx, mAP3), 1.0f);
        const float wy0 = A_*(ty*sy2);
        const float wy3 = A_*(sy*ty2);
        const float wy1 = fmaf(ty2, fmaf(AP2, ty, mAP3), 1.0f);
        const float wy2 = fmaf(sy2, fmaf(AP2, sy, mAP3), 1.0f);

        float acc;
        if (fasts[S]) {
            const float4 q0 = qg[S][0], q1 = qg[S][1], q2 = qg[S][2], q3 = qg[S][3];
            const float a0 = fmaf(wx3,q0.w, fmaf(wx2,q0.z, fmaf(wx1,q0.y, wx0*q0.x)));
            const float a1 = fmaf(wx3,q1.w, fmaf(wx2,q1.z, fmaf(wx1,q1.y, wx0*q1.x)));
            const float a2 = fmaf(wx3,q2.w, fmaf(wx2,q2.z, fmaf(wx1,q2.y, wx0*q2.x)));
            const float a3 = fmaf(wx3,q3.w, fmaf(wx2,q3.z, fmaf(wx1,q3.y, wx0*q3.x)));
            acc = fmaf(wy3,a3, fmaf(wy2,a2, fmaf(wy1,a1, wy0*a0)));
        } else {
            const float wxa[4] = {wx0, wx1, wx2, wx3};
            const float wya[4] = {wy0, wy1, wy2, wy3};
            const int ixi = ixis[S], iyi = iyis[S];
            acc = 0.0f;
            #pragma unroll
            for (int ky = 0; ky < 4; ++ky) {
                const int row = iyi - 1 + ky;
                const int gr  = gr0 + row;
                const bool rok = (row >= 0) & (row < CSP) & (gr >= 0) & (gr < AH);
                float racc = 0.0f;
                #pragma unroll
                for (int kx = 0; kx < 4; ++kx) {
                    const int col = ixi - 1 + kx;
                    const int gc  = gc0 + col;
                    const bool cok = rok & (col >= 0) & (col < CSP) & (gc >= 0) & (gc < AW);
                    const float v = cok ? matrix[(size_t)gr*AW + gc] : 0.0f;
                    racc = fmaf(wxa[kx], v, racc);
                }
                acc = fmaf(wya[ky], racc, acc);
            }
        }
        if (h0 + k < AH) __builtin_nontemporal_store(acc, &out[oidx]);
        oidx += AW;
    }
}

extern "C" void kernel_launch(void* const* d_in, const int* in_sizes, int n_in,
                              void* d_out, int out_size, void* d_ws, size_t ws_size,
                              hipStream_t stream) {
    const float* matrix = (const float*)d_in[0];
    const float* theta  = (const float*)d_in[1];
    float* out = (float*)d_out;

    dim3 block(64, 1, 1);
    dim3 grid(NBLK, 1, 1);   // flat, swizzled in-kernel; one wave per block
    shift_bicubic_kernel<<<grid, block, 0, stream>>>(matrix, theta, out);
}

// Round 13
// 44.974 us; speedup vs baseline: 3.3743x; 3.3743x over previous
//
#include <hip/hip_runtime.h>

#define PAD 10
#define CS 128
#define CSP 148           // CS + 2*PAD
#define AH 4000
#define AW 4000
#define RPT 8             // output rows per thread
#define BROWS 16          // rows per block (2 row-groups of RPT)
#define NBANDS 8
#define NBLK (1024*NBANDS)   // 8192, divisible by 8 XCDs

// depth-3 rolling pipeline, templated on block-uniform LEAN:
//   LEAN: footprint proven interior (tile window AND matrix) for every pixel
//         -> no per-pixel flag, no clamps, 32-bit offsets, branchless consume
//   !LEAN: R5/R9/R11-verified general path (clamped prefetch + checked fallback)
template<bool LEAN>
__device__ __forceinline__ void run_rows(
    const float* __restrict__ matrix, float* __restrict__ out,
    float ixf0, float iyf0, float t01, float t11,
    int gr0, int gc0, int lo_c, int hi_c, int lo_r, int hi_r,
    int h0, int oidx0)
{
    float  txs[3], tys[3];
    int    ixis[3], iyis[3];
    bool   fasts[3];
    float4 qg[3][4];

#define PREP_ANY(S, IXF, IYF)                                                 \
    do {                                                                      \
        const float fx0_ = floorf(IXF), fy0_ = floorf(IYF);                   \
        txs[S] = (IXF) - fx0_; tys[S] = (IYF) - fy0_;                         \
        const int ixi_ = (int)fx0_, iyi_ = (int)fy0_;                         \
        if (LEAN) {                                                           \
            const int off_ = (gr0 + iyi_ - 1)*AW + (gc0 + ixi_ - 1);          \
            const float* p_ = matrix + off_;                                  \
            __builtin_memcpy(&qg[S][0], p_,        16);                       \
            __builtin_memcpy(&qg[S][1], p_ + AW,   16);                       \
            __builtin_memcpy(&qg[S][2], p_ + 2*AW, 16);                       \
            __builtin_memcpy(&qg[S][3], p_ + 3*AW, 16);                       \
        } else {                                                              \
            ixis[S] = ixi_; iyis[S] = iyi_;                                   \
            fasts[S] = (ixi_ - 1 >= lo_c) & (ixi_ + 2 <= hi_c) &              \
                       (iyi_ - 1 >= lo_r) & (iyi_ + 2 <= hi_r);               \
            int mr_ = gr0 + iyi_ - 1; mr_ = mr_ < 0 ? 0 : (mr_ > AH-4 ? AH-4 : mr_); \
            int mc_ = gc0 + ixi_ - 1; mc_ = mc_ < 0 ? 0 : (mc_ > AW-4 ? AW-4 : mc_); \
            const float* p_ = matrix + (mr_*AW + mc_);                        \
            __builtin_memcpy(&qg[S][0], p_,        16);                       \
            __builtin_memcpy(&qg[S][1], p_ + AW,   16);                       \
            __builtin_memcpy(&qg[S][2], p_ + 2*AW, 16);                       \
            __builtin_memcpy(&qg[S][3], p_ + 3*AW, 16);                       \
        }                                                                     \
    } while (0)

    PREP_ANY(0, ixf0, iyf0);
    PREP_ANY(1, ixf0 + t01, iyf0 + t11);

    int oidx = oidx0;
    #pragma unroll
    for (int k = 0; k < RPT; ++k) {
        if (k + 2 < RPT) {
            const float ixfn = fmaf((float)(k+2), t01, ixf0);
            const float iyfn = fmaf((float)(k+2), t11, iyf0);
            PREP_ANY((k+2)%3, ixfn, iyfn);
        }
        // fence: loads above may not sink; consumers below may not hoist
        __builtin_amdgcn_sched_barrier(0);

        const int   S  = k % 3;
        const float tx = txs[S], ty = tys[S];
        const float A_ = -0.75f, AP2 = 1.25f, mAP3 = -2.25f;
        const float sx = 1.0f - tx, sy = 1.0f - ty;
        const float tx2 = tx*tx, sx2 = sx*sx;
        const float ty2 = ty*ty, sy2 = sy*sy;
        const float wx0 = A_*(tx*sx2);
        const float wx3 = A_*(sx*tx2);
        const float wx1 = fmaf(tx2, fmaf(AP2, tx, mAP3), 1.0f);
        const float wx2 = fmaf(sx2, fmaf(AP2, sx, mAP3), 1.0f);
        const float wy0 = A_*(ty*sy2);
        const float wy3 = A_*(sy*ty2);
        const float wy1 = fmaf(ty2, fmaf(AP2, ty, mAP3), 1.0f);
        const float wy2 = fmaf(sy2, fmaf(AP2, sy, mAP3), 1.0f);

        float acc;
        if (LEAN || fasts[S]) {
            const float4 q0 = qg[S][0], q1 = qg[S][1], q2 = qg[S][2], q3 = qg[S][3];
            const float a0 = fmaf(wx3,q0.w, fmaf(wx2,q0.z, fmaf(wx1,q0.y, wx0*q0.x)));
            const float a1 = fmaf(wx3,q1.w, fmaf(wx2,q1.z, fmaf(wx1,q1.y, wx0*q1.x)));
            const float a2 = fmaf(wx3,q2.w, fmaf(wx2,q2.z, fmaf(wx1,q2.y, wx0*q2.x)));
            const float a3 = fmaf(wx3,q3.w, fmaf(wx2,q3.z, fmaf(wx1,q3.y, wx0*q3.x)));
            acc = fmaf(wy3,a3, fmaf(wy2,a2, fmaf(wy1,a1, wy0*a0)));
        } else {
            const float wxa[4] = {wx0, wx1, wx2, wx3};
            const float wya[4] = {wy0, wy1, wy2, wy3};
            const int ixi = ixis[S], iyi = iyis[S];
            acc = 0.0f;
            #pragma unroll
            for (int ky = 0; ky < 4; ++ky) {
                const int row = iyi - 1 + ky;
                const int gr  = gr0 + row;
                const bool rok = (row >= 0) & (row < CSP) & (gr >= 0) & (gr < AH);
                float racc = 0.0f;
                #pragma unroll
                for (int kx = 0; kx < 4; ++kx) {
                    const int col = ixi - 1 + kx;
                    const int gc  = gc0 + col;
                    const bool cok = rok & (col >= 0) & (col < CSP) & (gc >= 0) & (gc < AW);
                    const float v = cok ? matrix[gr*AW + gc] : 0.0f;
                    racc = fmaf(wxa[kx], v, racc);
                }
                acc = fmaf(wya[ky], racc, acc);
            }
        }
        if (h0 + k < AH) __builtin_nontemporal_store(acc, &out[oidx]);
        oidx += AW;
    }
#undef PREP_ANY
}

__global__ __launch_bounds__(256) void shift_bicubic_kernel(
    const float* __restrict__ matrix,
    const float* __restrict__ theta,
    float* __restrict__ out)
{
    // XCD-contiguous swizzle (R8, verified: FETCH 40->31.5 MB)
    const int bid  = blockIdx.x;
    const int sid  = (bid & 7) * (NBLK/8) + (bid >> 3);
    const int tile = sid >> 3;          // 0..1023, row-major over 32x32 tiles
    const int band = sid & 7;           // 0..7
    const int i0   = tile >> 5;
    const int i1   = tile & 31;
    const int c    = threadIdx.x & 127;
    const int sub  = threadIdx.x >> 7;
    const int rb   = band * BROWS;
    const int r0   = rb + sub*RPT;
    const int w    = i1*CS + c;
    const int h0   = i0*CS + r0;
    if (w >= AW || h0 >= AH) return;

    const float t00 = theta[tile*6+0], t01 = theta[tile*6+1], t02 = theta[tile*6+2];
    const float t10 = theta[tile*6+3], t11 = theta[tile*6+4], t12 = theta[tile*6+5];

    const float xs  = (2.0f*(float)(c + PAD) + 1.0f) * (1.0f/148.0f) - 1.0f;
    const float ys0 = (2.0f*(float)(r0 + PAD) + 1.0f) * (1.0f/148.0f) - 1.0f;
    const float bx  = fmaf(t00, xs, t02);
    const float by  = fmaf(t10, xs, t12);
    // sample coords advance by exactly t01/t11 per output row
    const float ixf0 = fmaf(fmaf(t01, ys0, bx), 74.0f, 73.5f);
    const float iyf0 = fmaf(fmaf(t11, ys0, by), 74.0f, 73.5f);

    const int gr0 = i0*CS - 2*PAD;
    const int gc0 = i1*CS - 2*PAD;
    const int lo_c = (gc0 < 0) ? -gc0 : 0;
    const int hi_c = (gc0 + CSP - 1 > AW - 1) ? (AW - 1 - gc0) : (CSP - 1);
    const int lo_r = (gr0 < 0) ? -gr0 : 0;
    const int hi_r = (gr0 + CSP - 1 > AH - 1) ? (AH - 1 - gr0) : (CSP - 1);

    // ---- block-uniform allfast corner test (R6/R10, verified form) ----
    const int cact = (AW - 1 - i1*CS < CS - 1) ? (AW - 1 - i1*CS) : (CS - 1);
    const int ract = (rb + BROWS - 1 < AH - 1 - i0*CS) ? (rb + BROWS - 1)
                                                       : (AH - 1 - i0*CS);
    const float xsA = (2.0f*(float)(PAD)        + 1.0f)*(1.0f/148.0f) - 1.0f;
    const float xsB = (2.0f*(float)(cact + PAD) + 1.0f)*(1.0f/148.0f) - 1.0f;
    const float ysA = (2.0f*(float)(rb   + PAD) + 1.0f)*(1.0f/148.0f) - 1.0f;
    const float ysB = (2.0f*(float)(ract + PAD) + 1.0f)*(1.0f/148.0f) - 1.0f;
    const float ixAA = fmaf(fmaf(t01, ysA, fmaf(t00, xsA, t02)), 74.0f, 73.5f);
    const float ixAB = fmaf(fmaf(t01, ysB, fmaf(t00, xsA, t02)), 74.0f, 73.5f);
    const float ixBA = fmaf(fmaf(t01, ysA, fmaf(t00, xsB, t02)), 74.0f, 73.5f);
    const float ixBB = fmaf(fmaf(t01, ysB, fmaf(t00, xsB, t02)), 74.0f, 73.5f);
    const float iyAA = fmaf(fmaf(t11, ysA, fmaf(t10, xsA, t12)), 74.0f, 73.5f);
    const float iyAB = fmaf(fmaf(t11, ysB, fmaf(t10, xsA, t12)), 74.0f, 73.5f);
    const float iyBA = fmaf(fmaf(t11, ysA, fmaf(t10, xsB, t12)), 74.0f, 73.5f);
    const float iyBB = fmaf(fmaf(t11, ysB, fmaf(t10, xsB, t12)), 74.0f, 73.5f);
    const float ixmn = fminf(fminf(ixAA, ixAB), fminf(ixBA, ixBB));
    const float ixmx = fmaxf(fmaxf(ixAA, ixAB), fmaxf(ixBA, ixBB));
    const float iymn = fminf(fminf(iyAA, iyAB), fminf(iyBA, iyBB));
    const float iymx = fmaxf(fmaxf(iyAA, iyAB), fmaxf(iyBA, iyBB));
    const bool allfast =
        (ixmn >= (float)(lo_c + 1) + 0.01f) & (ixmx <= (float)(hi_c - 1) - 0.01f) &
        (iymn >= (float)(lo_r + 1) + 0.01f) & (iymx <= (float)(hi_r - 1) - 0.01f);

    const int oidx0 = h0*AW + w;
    if (allfast)
        run_rows<true >(matrix, out, ixf0, iyf0, t01, t11,
                        gr0, gc0, lo_c, hi_c, lo_r, hi_r, h0, oidx0);
    else
        run_rows<false>(matrix, out, ixf0, iyf0, t01, t11,
                        gr0, gc0, lo_c, hi_c, lo_r, hi_r, h0, oidx0);
}

extern "C" void kernel_launch(void* const* d_in, const int* in_sizes, int n_in,
                              void* d_out, int out_size, void* d_ws, size_t ws_size,
                              hipStream_t stream) {
    const float* matrix = (const float*)d_in[0];
    const float* theta  = (const float*)d_in[1];
    float* out = (float*)d_out;

    dim3 block(256, 1, 1);
    dim3 grid(NBLK, 1, 1);   // flat, swizzled in-kernel
    shift_bicubic_kernel<<<grid, block, 0, stream>>>(matrix, theta, out);
}

// Round 14
// 43.338 us; speedup vs baseline: 3.5018x; 1.0378x over previous
//
#include <hip/hip_runtime.h>

#define PAD 10
#define CS 128
#define CSP 148           // CS + 2*PAD
#define AH 4000
#define AW 4000
#define RPT 8             // output rows per thread
#define BROWS 16          // rows per block (2 row-groups of RPT)
#define NBANDS 8
#define NBLK (1024*NBANDS)   // 8192, divisible by 8 XCDs

typedef float v2f __attribute__((ext_vector_type(2)));

__device__ __forceinline__ v2f pk_fma(v2f a, v2f b, v2f c) {
    return __builtin_elementwise_fma(a, b, c);
}

// depth-3 rolling PREP (R11, verified): coords, fast flag, 4 clamped loads
#define PREPG(S, IXF, IYF)                                                    \
    do {                                                                      \
        const float fx0_ = floorf(IXF), fy0_ = floorf(IYF);                   \
        txs[S] = (IXF) - fx0_; tys[S] = (IYF) - fy0_;                         \
        const int ixi_ = (int)fx0_, iyi_ = (int)fy0_;                         \
        ixis[S] = ixi_; iyis[S] = iyi_;                                       \
        fasts[S] = (ixi_ - 1 >= lo_c) & (ixi_ + 2 <= hi_c) &                  \
                   (iyi_ - 1 >= lo_r) & (iyi_ + 2 <= hi_r);                   \
        int mr_ = gr0 + iyi_ - 1; mr_ = mr_ < 0 ? 0 : (mr_ > AH-4 ? AH-4 : mr_); \
        int mc_ = gc0 + ixi_ - 1; mc_ = mc_ < 0 ? 0 : (mc_ > AW-4 ? AW-4 : mc_); \
        const float* p_ = matrix + (size_t)mr_ * AW + mc_;                    \
        __builtin_memcpy(&qg[S][0], p_,        16);                           \
        __builtin_memcpy(&qg[S][1], p_ + AW,   16);                           \
        __builtin_memcpy(&qg[S][2], p_ + 2*AW, 16);                           \
        __builtin_memcpy(&qg[S][3], p_ + 3*AW, 16);                           \
    } while (0)

__global__ __launch_bounds__(256) void shift_bicubic_kernel(
    const float* __restrict__ matrix,
    const float* __restrict__ theta,
    float* __restrict__ out)
{
    // XCD-contiguous swizzle (R8, verified: FETCH 40->31.5 MB)
    const int bid  = blockIdx.x;
    const int sid  = (bid & 7) * (NBLK/8) + (bid >> 3);
    const int tile = sid >> 3;          // 0..1023, row-major over 32x32 tiles
    const int band = sid & 7;           // 0..7
    const int i0   = tile >> 5;
    const int i1   = tile & 31;
    const int c    = threadIdx.x & 127;
    const int sub  = threadIdx.x >> 7;
    const int rb   = band * BROWS;
    const int r0   = rb + sub*RPT;
    const int w    = i1*CS + c;
    const int h0   = i0*CS + r0;
    if (w >= AW || h0 >= AH) return;

    const float t00 = theta[tile*6+0], t01 = theta[tile*6+1], t02 = theta[tile*6+2];
    const float t10 = theta[tile*6+3], t11 = theta[tile*6+4], t12 = theta[tile*6+5];

    const float xs  = (2.0f*(float)(c + PAD) + 1.0f) * (1.0f/148.0f) - 1.0f;
    const float ys0 = (2.0f*(float)(r0 + PAD) + 1.0f) * (1.0f/148.0f) - 1.0f;
    const float bx  = fmaf(t00, xs, t02);
    const float by  = fmaf(t10, xs, t12);
    // sample coords advance by exactly t01/t11 per output row
    const float ixf0 = fmaf(fmaf(t01, ys0, bx), 74.0f, 73.5f);
    const float iyf0 = fmaf(fmaf(t11, ys0, by), 74.0f, 73.5f);

    const int gr0 = i0*CS - 2*PAD;
    const int gc0 = i1*CS - 2*PAD;
    const int lo_c = (gc0 < 0) ? -gc0 : 0;
    const int hi_c = (gc0 + CSP - 1 > AW - 1) ? (AW - 1 - gc0) : (CSP - 1);
    const int lo_r = (gr0 < 0) ? -gr0 : 0;
    const int hi_r = (gr0 + CSP - 1 > AH - 1) ? (AH - 1 - gr0) : (CSP - 1);

    // depth-3 rolling pipeline state
    float  txs[3], tys[3];
    int    ixis[3], iyis[3];
    bool   fasts[3];
    float4 qg[3][4];

    PREPG(0, ixf0, iyf0);
    {
        const float ixf1 = ixf0 + t01;
        const float iyf1 = iyf0 + t11;
        PREPG(1, ixf1, iyf1);
    }

    int oidx = h0*AW + w;
    #pragma unroll
    for (int k = 0; k < RPT; ++k) {
        // ---- issue pixel k+2's loads (slot (k+2)%3) ----
        if (k + 2 < RPT) {
            const float ixfn = fmaf((float)(k+2), t01, ixf0);
            const float iyfn = fmaf((float)(k+2), t11, iyf0);
            PREPG((k+2)%3, ixfn, iyfn);
        }
        // fence: loads above may not sink; consumers below may not hoist
        __builtin_amdgcn_sched_barrier(0);

        // ---- consume slot k%3 (packed-f32 math) ----
        const int   S  = k % 3;
        const float tx = txs[S], ty = tys[S];

        // x-axis weights, packed: px={tx,sx}; {wx0,wx3}=-0.75*px*swap(px^2);
        // {wx1,wx2}=fma(px^2, fma(1.25,px,-2.25), 1)
        const v2f px   = {tx, 1.0f - tx};
        const v2f px2  = px*px;
        const v2f px2s = {px2.y, px2.x};
        const v2f wx03 = (-0.75f) * (px * px2s);            // {wx0, wx3}
        const v2f wx12 = pk_fma(px2,
                           pk_fma(px, (v2f){1.25f,1.25f}, (v2f){-2.25f,-2.25f}),
                           (v2f){1.0f,1.0f});               // {wx1, wx2}
        const v2f py   = {ty, 1.0f - ty};
        const v2f py2  = py*py;
        const v2f py2s = {py2.y, py2.x};
        const v2f wy03 = (-0.75f) * (py * py2s);            // {wy0, wy3}
        const v2f wy12 = pk_fma(py2,
                           pk_fma(py, (v2f){1.25f,1.25f}, (v2f){-2.25f,-2.25f}),
                           (v2f){1.0f,1.0f});               // {wy1, wy2}

        // tap-aligned x-weight pairs (built once per pixel)
        const v2f wxA = {wx03.x, wx12.x};   // {wx0, wx1}  for q.xy
        const v2f wxB = {wx12.y, wx03.y};   // {wx2, wx3}  for q.zw
        const float wy0 = wy03.x, wy1 = wy12.x, wy2 = wy12.y, wy3 = wy03.y;

        float acc;
        if (fasts[S]) {
            const float4 q0 = qg[S][0], q1 = qg[S][1], q2 = qg[S][2], q3 = qg[S][3];
            const v2f s0 = pk_fma(wxA, (v2f){q0.x,q0.y}, wxB*(v2f){q0.z,q0.w});
            const v2f s1 = pk_fma(wxA, (v2f){q1.x,q1.y}, wxB*(v2f){q1.z,q1.w});
            const v2f s2 = pk_fma(wxA, (v2f){q2.x,q2.y}, wxB*(v2f){q2.z,q2.w});
            const v2f s3 = pk_fma(wxA, (v2f){q3.x,q3.y}, wxB*(v2f){q3.z,q3.w});
            v2f accp = (v2f){wy0,wy0} * s0;
            accp = pk_fma((v2f){wy1,wy1}, s1, accp);
            accp = pk_fma((v2f){wy2,wy2}, s2, accp);
            accp = pk_fma((v2f){wy3,wy3}, s3, accp);
            acc = accp.x + accp.y;
        } else {
            const float wxa[4] = {wx03.x, wx12.x, wx12.y, wx03.y};
            const float wya[4] = {wy0, wy1, wy2, wy3};
            const int ixi = ixis[S], iyi = iyis[S];
            acc = 0.0f;
            #pragma unroll
            for (int ky = 0; ky < 4; ++ky) {
                const int row = iyi - 1 + ky;
                const int gr  = gr0 + row;
                const bool rok = (row >= 0) & (row < CSP) & (gr >= 0) & (gr < AH);
                float racc = 0.0f;
                #pragma unroll
                for (int kx = 0; kx < 4; ++kx) {
                    const int col = ixi - 1 + kx;
                    const int gc  = gc0 + col;
                    const bool cok = rok & (col >= 0) & (col < CSP) & (gc >= 0) & (gc < AW);
                    const float v = cok ? matrix[(size_t)gr*AW + gc] : 0.0f;
                    racc = fmaf(wxa[kx], v, racc);
                }
                acc = fmaf(wya[ky], racc, acc);
            }
        }
        if (h0 + k < AH) __builtin_nontemporal_store(acc, &out[oidx]);
        oidx += AW;
    }
}

extern "C" void kernel_launch(void* const* d_in, const int* in_sizes, int n_in,
                              void* d_out, int out_size, void* d_ws, size_t ws_size,
                              hipStream_t stream) {
    const float* matrix = (const float*)d_in[0];
    const float* theta  = (const float*)d_in[1];
    float* out = (float*)d_out;

    dim3 block(256, 1, 1);
    dim3 grid(NBLK, 1, 1);   // flat, swizzled in-kernel
    shift_bicubic_kernel<<<grid, block, 0, stream>>>(matrix, theta, out);
}

// Round 15
// 42.047 us; speedup vs baseline: 3.6093x; 1.0307x over previous
//
#include <hip/hip_runtime.h>

#define PAD 10
#define CS 128
#define CSP 148           // CS + 2*PAD
#define AH 4000
#define AW 4000
#define RPT 8             // output rows per thread
#define BROWS 8           // rows per block (ONE row-group of RPT)
#define NBANDS 16
#define NBLK (1024*NBANDS)   // 16384, divisible by 8 XCDs

// depth-3 rolling PREP (R11, verified): coords, fast flag, 4 clamped loads
#define PREPG(S, IXF, IYF)                                                    \
    do {                                                                      \
        const float fx0_ = floorf(IXF), fy0_ = floorf(IYF);                   \
        txs[S] = (IXF) - fx0_; tys[S] = (IYF) - fy0_;                         \
        const int ixi_ = (int)fx0_, iyi_ = (int)fy0_;                         \
        ixis[S] = ixi_; iyis[S] = iyi_;                                       \
        fasts[S] = (ixi_ - 1 >= lo_c) & (ixi_ + 2 <= hi_c) &                  \
                   (iyi_ - 1 >= lo_r) & (iyi_ + 2 <= hi_r);                   \
        int mr_ = gr0 + iyi_ - 1; mr_ = mr_ < 0 ? 0 : (mr_ > AH-4 ? AH-4 : mr_); \
        int mc_ = gc0 + ixi_ - 1; mc_ = mc_ < 0 ? 0 : (mc_ > AW-4 ? AW-4 : mc_); \
        const float* p_ = matrix + (mr_ * AW + mc_);                          \
        __builtin_memcpy(&qg[S][0], p_,        16);                           \
        __builtin_memcpy(&qg[S][1], p_ + AW,   16);                           \
        __builtin_memcpy(&qg[S][2], p_ + 2*AW, 16);                           \
        __builtin_memcpy(&qg[S][3], p_ + 3*AW, 16);                           \
    } while (0)

__global__ __launch_bounds__(128) void shift_bicubic_kernel(
    const float* __restrict__ matrix,
    const float* __restrict__ theta,
    float* __restrict__ out)
{
    // XCD-contiguous swizzle (R8, verified: FETCH 40->31.5 MB):
    // XCD k owns sids [k*2048,(k+1)*2048) = a 4-tile-row horizontal stripe;
    // tile-major/band-minor so consecutive blocks on a CU share a tile.
    const int bid  = blockIdx.x;
    const int sid  = (bid & 7) * (NBLK/8) + (bid >> 3);
    const int tile = sid >> 4;          // 0..1023, row-major over 32x32 tiles
    const int band = sid & 15;          // 0..15
    const int i0   = tile >> 5;
    const int i1   = tile & 31;
    const int c    = threadIdx.x;       // 0..127: column within tile
    const int rb   = band * BROWS;
    const int r0   = rb;                // this block's (only) row-group
    const int w    = i1*CS + c;
    const int h0   = i0*CS + r0;
    if (w >= AW || h0 >= AH) return;

    const float t00 = theta[tile*6+0], t01 = theta[tile*6+1], t02 = theta[tile*6+2];
    const float t10 = theta[tile*6+3], t11 = theta[tile*6+4], t12 = theta[tile*6+5];

    const float xs  = (2.0f*(float)(c + PAD) + 1.0f) * (1.0f/148.0f) - 1.0f;
    const float ys0 = (2.0f*(float)(r0 + PAD) + 1.0f) * (1.0f/148.0f) - 1.0f;
    const float bx  = fmaf(t00, xs, t02);
    const float by  = fmaf(t10, xs, t12);
    // sample coords advance by exactly t01/t11 per output row
    const float ixf0 = fmaf(fmaf(t01, ys0, bx), 74.0f, 73.5f);
    const float iyf0 = fmaf(fmaf(t11, ys0, by), 74.0f, 73.5f);

    const int gr0 = i0*CS - 2*PAD;
    const int gc0 = i1*CS - 2*PAD;
    const int lo_c = (gc0 < 0) ? -gc0 : 0;
    const int hi_c = (gc0 + CSP - 1 > AW - 1) ? (AW - 1 - gc0) : (CSP - 1);
    const int lo_r = (gr0 < 0) ? -gr0 : 0;
    const int hi_r = (gr0 + CSP - 1 > AH - 1) ? (AH - 1 - gr0) : (CSP - 1);

    // depth-3 rolling pipeline state
    float  txs[3], tys[3];
    int    ixis[3], iyis[3];
    bool   fasts[3];
    float4 qg[3][4];

    PREPG(0, ixf0, iyf0);
    {
        const float ixf1 = ixf0 + t01;
        const float iyf1 = iyf0 + t11;
        PREPG(1, ixf1, iyf1);
    }

    int oidx = h0*AW + w;
    #pragma unroll
    for (int k = 0; k < RPT; ++k) {
        // ---- issue pixel k+2's loads (slot (k+2)%3) ----
        if (k + 2 < RPT) {
            const float ixfn = fmaf((float)(k+2), t01, ixf0);
            const float iyfn = fmaf((float)(k+2), t11, iyf0);
            PREPG((k+2)%3, ixfn, iyfn);
        }
        // fence: loads above may not sink; consumers below may not hoist
        __builtin_amdgcn_sched_barrier(0);

        // ---- consume slot k%3 ----
        const int   S  = k % 3;
        const float tx = txs[S], ty = tys[S];
        const float A_ = -0.75f, AP2 = 1.25f, mAP3 = -2.25f;
        const float sx = 1.0f - tx, sy = 1.0f - ty;
        const float tx2 = tx*tx, sx2 = sx*sx;
        const float ty2 = ty*ty, sy2 = sy*sy;
        const float wx0 = A_*(tx*sx2);
        const float wx3 = A_*(sx*tx2);
        const float wx1 = fmaf(tx2, fmaf(AP2, tx, mAP3), 1.0f);
        const float wx2 = fmaf(sx2, fmaf(AP2, sx, mAP3), 1.0f);
        const float wy0 = A_*(ty*sy2);
        const float wy3 = A_*(sy*ty2);
        const float wy1 = fmaf(ty2, fmaf(AP2, ty, mAP3), 1.0f);
        const float wy2 = fmaf(sy2, fmaf(AP2, sy, mAP3), 1.0f);

        float acc;
        if (fasts[S]) {
            const float4 q0 = qg[S][0], q1 = qg[S][1], q2 = qg[S][2], q3 = qg[S][3];
            const float a0 = fmaf(wx3,q0.w, fmaf(wx2,q0.z, fmaf(wx1,q0.y, wx0*q0.x)));
            const float a1 = fmaf(wx3,q1.w, fmaf(wx2,q1.z, fmaf(wx1,q1.y, wx0*q1.x)));
            const float a2 = fmaf(wx3,q2.w, fmaf(wx2,q2.z, fmaf(wx1,q2.y, wx0*q2.x)));
            const float a3 = fmaf(wx3,q3.w, fmaf(wx2,q3.z, fmaf(wx1,q3.y, wx0*q3.x)));
            acc = fmaf(wy3,a3, fmaf(wy2,a2, fmaf(wy1,a1, wy0*a0)));
        } else {
            const float wxa[4] = {wx0, wx1, wx2, wx3};
            const float wya[4] = {wy0, wy1, wy2, wy3};
            const int ixi = ixis[S], iyi = iyis[S];
            acc = 0.0f;
            #pragma unroll
            for (int ky = 0; ky < 4; ++ky) {
                const int row = iyi - 1 + ky;
                const int gr  = gr0 + row;
                const bool rok = (row >= 0) & (row < CSP) & (gr >= 0) & (gr < AH);
                float racc = 0.0f;
                #pragma unroll
                for (int kx = 0; kx < 4; ++kx) {
                    const int col = ixi - 1 + kx;
                    const int gc  = gc0 + col;
                    const bool cok = rok & (col >= 0) & (col < CSP) & (gc >= 0) & (gc < AW);
                    const float v = cok ? matrix[gr*AW + gc] : 0.0f;
                    racc = fmaf(wxa[kx], v, racc);
                }
                acc = fmaf(wya[ky], racc, acc);
            }
        }
        if (h0 + k < AH) __builtin_nontemporal_store(acc, &out[oidx]);
        oidx += AW;
    }
}

extern "C" void kernel_launch(void* const* d_in, const int* in_sizes, int n_in,
                              void* d_out, int out_size, void* d_ws, size_t ws_size,
                              hipStream_t stream) {
    const float* matrix = (const float*)d_in[0];
    const float* theta  = (const float*)d_in[1];
    float* out = (float*)d_out;

    dim3 block(128, 1, 1);
    dim3 grid(NBLK, 1, 1);   // flat, swizzled in-kernel; 2 waves per block
    shift_bicubic_kernel<<<grid, block, 0, stream>>>(matrix, theta, out);
}